// Round 10
// baseline (107.765 us; speedup 1.0000x reference)
//
#include <hip/hip_runtime.h>

// AdditiveAttention: scores[b,h,q,k] = sum_d V[d]*tanh(Wq[q,d]+Wk[k,d]) + bV
// B=2 H=8 Lq=Lk=512 D=64.
//
// tanh(x) = 1 - 2/(1+e^{2x}); e^{2(a+b)} = e^{2a}*e^{2b}: exp2 lives in the
// O(L*D) projection pass. Score inner loop: rational-tree division sharing,
// R10 = one rcp per SIXTEEN elements (HEX = two OCT sub-trees + 1 combine):
// 62 VALU + 1 trans per 16 elems. Validated issue model (R6->R7 A/B):
// v_rcp_f32 serializes on the issue port at ~16 cyc; FMA 2 cyc; sustained
// issue factor ~0.65 (m07). Floor ~25us, prev measured ~31us.
//
// R10 vs R9: HEX (halve trans again: -12 cyc/16elems), full unroll of the
// 4x16-dim d-loop (all ds_read offsets compile-time), launch_bounds(512,2)
// for VGPR headroom (LDS 52KB already caps 2 blocks/CU).

#define BH 16
#define L 512
#define D 64
#define C_SCALE 2.8853900817779268f  // 2*log2(e)

__global__ __launch_bounds__(256) void proj_kernel(
    const float* __restrict__ Q, const float* __restrict__ K,
    const float* __restrict__ W1, const float* __restrict__ b1,
    const float* __restrict__ W2, const float* __restrict__ b2,
    float* __restrict__ eq_all, float* __restrict__ ek_all)
{
    // 1024 blocks: first 512 project Q (16 rows each), last 512 project K.
    // Output: E = exp2(C * (X@W + b)), row-major [row][d].
    int blk = blockIdx.x;
    bool isK = blk >= 512;
    const float* __restrict__ X  = isK ? K  : Q;
    const float* __restrict__ W  = isK ? W2 : W1;
    const float* __restrict__ bb = isK ? b2 : b1;
    float* __restrict__ O = isK ? ek_all : eq_all;
    int rb = (isK ? blk - 512 : blk) * 16;

    __shared__ float ws[64][68];   // W staged once per block (16KB from L2)
    __shared__ float xs[16][68];   // 16 input rows

    int tid = threadIdx.x;
    const float4* __restrict__ Wg = (const float4*)W;
    #pragma unroll
    for (int i = 0; i < 4; ++i) {          // 1024 float4 = 16KB, coalesced
        int idx = tid + i * 256;
        int r = idx >> 4, c4 = idx & 15;
        *(float4*)&ws[r][c4 * 4] = Wg[idx];    // 2-way bank phase = free
    }
    {
        const float4* __restrict__ Xg = (const float4*)(X + rb * 64);
        int r = tid >> 4, c4 = tid & 15;
        *(float4*)&xs[r][c4 * 4] = Xg[tid];    // 256 float4, coalesced
    }
    __syncthreads();

    int lr = tid >> 4;   // row 0..15 (4-addr broadcast within wave)
    int cg = tid & 15;   // col-group: cols 4cg..4cg+3

    float4 acc = {0.f, 0.f, 0.f, 0.f};
    #pragma unroll
    for (int d = 0; d < 64; ++d) {
        float x = xs[lr][d];                       // broadcast read
        float4 w = *(const float4*)&ws[d][cg * 4]; // 2-way banks, free
        acc.x = fmaf(x, w.x, acc.x);
        acc.y = fmaf(x, w.y, acc.y);
        acc.z = fmaf(x, w.z, acc.z);
        acc.w = fmaf(x, w.w, acc.w);
    }
    float4 bbv = *(const float4*)(bb + cg * 4);
    float4 o;
    o.x = __builtin_amdgcn_exp2f((acc.x + bbv.x) * C_SCALE);
    o.y = __builtin_amdgcn_exp2f((acc.y + bbv.y) * C_SCALE);
    o.z = __builtin_amdgcn_exp2f((acc.z + bbv.z) * C_SCALE);
    o.w = __builtin_amdgcn_exp2f((acc.w + bbv.w) * C_SCALE);
    *(float4*)&O[(rb + lr) * 64 + cg * 4] = o;     // coalesced float4 store
}

// 8-element numerator/denominator sub-tree (29 VALU, no rcp).
#define OCT_ND(Nout, Dout, qa_, qb_, ka_, kb_, va_, vb_)            \
    float Nout, Dout;                                                \
    {                                                                \
        float d0_ = fmaf((qa_).x, (ka_).x, 1.0f);                    \
        float d1_ = fmaf((qa_).y, (ka_).y, 1.0f);                    \
        float d2_ = fmaf((qa_).z, (ka_).z, 1.0f);                    \
        float d3_ = fmaf((qa_).w, (ka_).w, 1.0f);                    \
        float d4_ = fmaf((qb_).x, (kb_).x, 1.0f);                    \
        float d5_ = fmaf((qb_).y, (kb_).y, 1.0f);                    \
        float d6_ = fmaf((qb_).z, (kb_).z, 1.0f);                    \
        float d7_ = fmaf((qb_).w, (kb_).w, 1.0f);                    \
        float dA1_ = d0_ * d1_;                                      \
        float dA2_ = d2_ * d3_;                                      \
        float dB1_ = d4_ * d5_;                                      \
        float dB2_ = d6_ * d7_;                                      \
        float nA1_ = fmaf((va_).x, d1_, (va_).y * d0_);              \
        float nA2_ = fmaf((va_).z, d3_, (va_).w * d2_);              \
        float nB1_ = fmaf((vb_).x, d5_, (vb_).y * d4_);              \
        float nB2_ = fmaf((vb_).z, d7_, (vb_).w * d6_);              \
        float DA_ = dA1_ * dA2_;                                     \
        float DB_ = dB1_ * dB2_;                                     \
        float NA_ = fmaf(nA2_, dA1_, nA1_ * dA2_);                   \
        float NB_ = fmaf(nB2_, dB1_, nB1_ * dB2_);                   \
        Nout = fmaf(NA_, DB_, NB_ * DA_);                            \
        Dout = DA_ * DB_;                                            \
    }

// 16 elements, ONE rcp: 62 VALU + 1 trans.
#define HEX(accref, qa_, qb_, qc_, qd_, ka_, kb_, kc_, kd_)         \
    {                                                                \
        OCT_ND(NA_h, DA_h, qa_, qb_, ka_, kb_, vva, vvb);            \
        OCT_ND(NB_h, DB_h, qc_, qd_, kc_, kd_, vvc, vvd);            \
        float num_ = fmaf(NA_h, DB_h, NB_h * DA_h);                  \
        float rc_  = __builtin_amdgcn_rcpf(DA_h * DB_h);             \
        (accref)   = fmaf(num_, rc_, (accref));                      \
    }

__global__ __launch_bounds__(512, 2) void score_kernel(
    const float* __restrict__ eq_all, const float* __restrict__ ek_all,
    const float* __restrict__ Vv, const float* __restrict__ bV,
    float* __restrict__ out)
{
    // Block = (bh, 128-q, 64-k), 512 threads. Thread: qg=tid>>4 (0..31) owns
    // q rows {qg+32i, i<4}; kg=tid&15 owns k rows {kg+16j, j<4}; acc[4][4].
    // LDS 52.2KB -> 2 blocks/CU; 512 blocks = exactly 2/CU, no tail.
    __shared__ float eq[128][68];  // row-major [q][d]; rows 272B
    __shared__ float ek[64][68];   // row-major [k][d]

    int tid = threadIdx.x;
    int blk = blockIdx.x;
    int kt = blk & 7;              // 8 k-tiles of 64
    int qt = (blk >> 3) & 3;       // 4 q-tiles of 128
    int bh = blk >> 5;

    const float4* __restrict__ eqg = (const float4*)(eq_all + (bh * L + qt * 128) * D);
    const float4* __restrict__ ekg = (const float4*)(ek_all + (bh * L + kt * 64) * D);

    #pragma unroll
    for (int i = 0; i < 6; ++i) {          // 192 rows x 16 float4 total
        int idx = tid + i * 512;
        int r = idx >> 4, c4 = idx & 15;
        if (r < 128) *(float4*)&eq[r][c4 * 4] = eqg[idx];
        else         *(float4*)&ek[r - 128][c4 * 4] = ekg[idx - 2048];
    }
    __syncthreads();

    int kg = tid & 15;
    int qg = tid >> 4;

    float acc[4][4] = {{0.f,0.f,0.f,0.f},{0.f,0.f,0.f,0.f},
                       {0.f,0.f,0.f,0.f},{0.f,0.f,0.f,0.f}};

    #pragma unroll
    for (int d16 = 0; d16 < 4; ++d16) {    // 16 dims per iter, FULL unroll
        // eq: 4-address x 16-lane broadcast (free)
        float4 vq0a = *(const float4*)&eq[qg     ][d16 * 16];
        float4 vq0b = *(const float4*)&eq[qg     ][d16 * 16 + 4];
        float4 vq0c = *(const float4*)&eq[qg     ][d16 * 16 + 8];
        float4 vq0d = *(const float4*)&eq[qg     ][d16 * 16 + 12];
        float4 vq1a = *(const float4*)&eq[qg + 32][d16 * 16];
        float4 vq1b = *(const float4*)&eq[qg + 32][d16 * 16 + 4];
        float4 vq1c = *(const float4*)&eq[qg + 32][d16 * 16 + 8];
        float4 vq1d = *(const float4*)&eq[qg + 32][d16 * 16 + 12];
        float4 vq2a = *(const float4*)&eq[qg + 64][d16 * 16];
        float4 vq2b = *(const float4*)&eq[qg + 64][d16 * 16 + 4];
        float4 vq2c = *(const float4*)&eq[qg + 64][d16 * 16 + 8];
        float4 vq2d = *(const float4*)&eq[qg + 64][d16 * 16 + 12];
        float4 vq3a = *(const float4*)&eq[qg + 96][d16 * 16];
        float4 vq3b = *(const float4*)&eq[qg + 96][d16 * 16 + 4];
        float4 vq3c = *(const float4*)&eq[qg + 96][d16 * 16 + 8];
        float4 vq3d = *(const float4*)&eq[qg + 96][d16 * 16 + 12];
        // wave-uniform address -> scalar loads (SGPR operands)
        float4 vva  = *(const float4*)(Vv + d16 * 16);
        float4 vvb  = *(const float4*)(Vv + d16 * 16 + 4);
        float4 vvc  = *(const float4*)(Vv + d16 * 16 + 8);
        float4 vvd  = *(const float4*)(Vv + d16 * 16 + 12);

        #pragma unroll
        for (int j = 0; j < 4; ++j) {      // ek: 16 rows, 2-way banks (free)
            float4 vka = *(const float4*)&ek[kg + 16 * j][d16 * 16];
            float4 vkb = *(const float4*)&ek[kg + 16 * j][d16 * 16 + 4];
            float4 vkc = *(const float4*)&ek[kg + 16 * j][d16 * 16 + 8];
            float4 vkd = *(const float4*)&ek[kg + 16 * j][d16 * 16 + 12];
            HEX(acc[0][j], vq0a, vq0b, vq0c, vq0d, vka, vkb, vkc, vkd);
            HEX(acc[1][j], vq1a, vq1b, vq1c, vq1d, vka, vkb, vkc, vkd);
            HEX(acc[2][j], vq2a, vq2b, vq2c, vq2d, vka, vkb, vkc, vkd);
            HEX(acc[3][j], vq3a, vq3b, vq3c, vq3d, vka, vkb, vkc, vkd);
        }
    }

    // sum(V): uniform scalar math, epilogue only
    float sv = 0.f;
    #pragma unroll
    for (int t = 0; t < 64; ++t) sv += Vv[t];

    // score = bV + sum(V) - 2 * sum_d V[d]/(1+e^{2x_d})
    float base = bV[0] + sv;
    int orow = (bh * L + qt * 128 + qg) * L + kt * 64 + kg;
    #pragma unroll
    for (int i = 0; i < 4; ++i) {
        #pragma unroll
        for (int j = 0; j < 4; ++j) {
            out[orow + (32 * i) * L + 16 * j] = fmaf(-2.f, acc[i][j], base);
        }
    }
}

extern "C" void kernel_launch(void* const* d_in, const int* in_sizes, int n_in,
                              void* d_out, int out_size, void* d_ws, size_t ws_size,
                              hipStream_t stream) {
    const float* Q  = (const float*)d_in[0];
    const float* K  = (const float*)d_in[1];
    const float* W1 = (const float*)d_in[2];
    const float* b1 = (const float*)d_in[3];
    const float* W2 = (const float*)d_in[4];
    const float* b2 = (const float*)d_in[5];
    const float* V  = (const float*)d_in[6];
    const float* bV = (const float*)d_in[7];
    float* out = (float*)d_out;

    float* eq_all = (float*)d_ws;                 // BH*L*D floats (2 MB)
    float* ek_all = eq_all + BH * L * D;          // BH*L*D floats (2 MB)

    proj_kernel<<<1024, 256, 0, stream>>>(Q, K, W1, b1, W2, b2, eq_all, ek_all);
    score_kernel<<<512, 512, 0, stream>>>(eq_all, ek_all, V, bV, out);
}

// Round 11
// 101.499 us; speedup vs baseline: 1.0617x; 1.0617x over previous
//
#include <hip/hip_runtime.h>

// AdditiveAttention: scores[b,h,q,k] = sum_d V[d]*tanh(Wq[q,d]+Wk[k,d]) + bV
// B=2 H=8 Lq=Lk=512 D=64.
//
// tanh(x) = 1 - 2/(1+e^{2x}); e^{2(a+b)} = e^{2a}*e^{2b}, so exp2 lives in
// the O(L*D) projection pass. Score inner loop: one rcp per EIGHT elements
// (OCT rational-tree): 30 VALU + 1 trans per 8 elems.
//
// Final model (validated R4-R10): score kernel is VALU-issue-bound at
// ~81% of the m07-calibrated practical FMA ceiling (~25us floor, ~31us
// measured). Neutral A/Bs: addressing (R4), LDS intensity (R5), occupancy
// (R6), LDS:VALU ratio (R8). Confirmed: trans-halving differential (R7,
// rcp ~16cyc serialized issue); proj W-staging (R9, -3.3us). Regression:
// HEX full-unroll (R10, +4.2us — VGPR pressure past the 128 cliff).
// This file = R9 verbatim (best: 103.6us total).

#define BH 16
#define L 512
#define D 64
#define C_SCALE 2.8853900817779268f  // 2*log2(e)

__global__ __launch_bounds__(256) void proj_kernel(
    const float* __restrict__ Q, const float* __restrict__ K,
    const float* __restrict__ W1, const float* __restrict__ b1,
    const float* __restrict__ W2, const float* __restrict__ b2,
    float* __restrict__ eq_all, float* __restrict__ ek_all)
{
    // 1024 blocks: first 512 project Q (16 rows each), last 512 project K.
    // Output: E = exp2(C * (X@W + b)), row-major [row][d].
    int blk = blockIdx.x;
    bool isK = blk >= 512;
    const float* __restrict__ X  = isK ? K  : Q;
    const float* __restrict__ W  = isK ? W2 : W1;
    const float* __restrict__ bb = isK ? b2 : b1;
    float* __restrict__ O = isK ? ek_all : eq_all;
    int rb = (isK ? blk - 512 : blk) * 16;

    __shared__ float ws[64][68];   // W staged once per block (16KB from L2)
    __shared__ float xs[16][68];   // 16 input rows

    int tid = threadIdx.x;
    const float4* __restrict__ Wg = (const float4*)W;
    #pragma unroll
    for (int i = 0; i < 4; ++i) {          // 1024 float4 = 16KB, coalesced
        int idx = tid + i * 256;
        int r = idx >> 4, c4 = idx & 15;
        *(float4*)&ws[r][c4 * 4] = Wg[idx];    // 2-way bank phase = free
    }
    {
        const float4* __restrict__ Xg = (const float4*)(X + rb * 64);
        int r = tid >> 4, c4 = tid & 15;
        *(float4*)&xs[r][c4 * 4] = Xg[tid];    // 256 float4, coalesced
    }
    __syncthreads();

    int lr = tid >> 4;   // row 0..15 (4-addr broadcast within wave)
    int cg = tid & 15;   // col-group: cols 4cg..4cg+3

    float4 acc = {0.f, 0.f, 0.f, 0.f};
    #pragma unroll
    for (int d = 0; d < 64; ++d) {
        float x = xs[lr][d];                       // broadcast read
        float4 w = *(const float4*)&ws[d][cg * 4]; // 2-way banks, free
        acc.x = fmaf(x, w.x, acc.x);
        acc.y = fmaf(x, w.y, acc.y);
        acc.z = fmaf(x, w.z, acc.z);
        acc.w = fmaf(x, w.w, acc.w);
    }
    float4 bbv = *(const float4*)(bb + cg * 4);
    float4 o;
    o.x = __builtin_amdgcn_exp2f((acc.x + bbv.x) * C_SCALE);
    o.y = __builtin_amdgcn_exp2f((acc.y + bbv.y) * C_SCALE);
    o.z = __builtin_amdgcn_exp2f((acc.z + bbv.z) * C_SCALE);
    o.w = __builtin_amdgcn_exp2f((acc.w + bbv.w) * C_SCALE);
    *(float4*)&O[(rb + lr) * 64 + cg * 4] = o;     // coalesced float4 store
}

// 8 elements, ONE rcp: 30 VALU + 1 trans.
#define OCT(accref, qa_, qb_, ka_, kb_, va_, vb_)                  \
    {                                                               \
        float d0_ = fmaf((qa_).x, (ka_).x, 1.0f);                   \
        float d1_ = fmaf((qa_).y, (ka_).y, 1.0f);                   \
        float d2_ = fmaf((qa_).z, (ka_).z, 1.0f);                   \
        float d3_ = fmaf((qa_).w, (ka_).w, 1.0f);                   \
        float d4_ = fmaf((qb_).x, (kb_).x, 1.0f);                   \
        float d5_ = fmaf((qb_).y, (kb_).y, 1.0f);                   \
        float d6_ = fmaf((qb_).z, (kb_).z, 1.0f);                   \
        float d7_ = fmaf((qb_).w, (kb_).w, 1.0f);                   \
        float dA1_ = d0_ * d1_;                                     \
        float dA2_ = d2_ * d3_;                                     \
        float dB1_ = d4_ * d5_;                                     \
        float dB2_ = d6_ * d7_;                                     \
        float nA1_ = fmaf((va_).x, d1_, (va_).y * d0_);             \
        float nA2_ = fmaf((va_).z, d3_, (va_).w * d2_);             \
        float nB1_ = fmaf((vb_).x, d5_, (vb_).y * d4_);             \
        float nB2_ = fmaf((vb_).z, d7_, (vb_).w * d6_);             \
        float DA_ = dA1_ * dA2_;                                    \
        float DB_ = dB1_ * dB2_;                                    \
        float NA_ = fmaf(nA2_, dA1_, nA1_ * dA2_);                  \
        float NB_ = fmaf(nB2_, dB1_, nB1_ * dB2_);                  \
        float num_ = fmaf(NA_, DB_, NB_ * DA_);                     \
        float rc_  = __builtin_amdgcn_rcpf(DA_ * DB_);              \
        (accref)   = fmaf(num_, rc_, (accref));                     \
    }

__global__ __launch_bounds__(512, 4) void score_kernel(
    const float* __restrict__ eq_all, const float* __restrict__ ek_all,
    const float* __restrict__ Vv, const float* __restrict__ bV,
    float* __restrict__ out)
{
    // Block = (bh, 128-q, 64-k), 512 threads. Thread: qg=tid>>4 (0..31) owns
    // q rows {qg+32i, i<4}; kg=tid&15 owns k rows {kg+16j, j<4}; acc[4][4].
    // LDS 52.2KB -> 2 blocks/CU; 512 blocks = exactly 2/CU, no tail.
    __shared__ float eq[128][68];  // row-major [q][d]; rows 272B
    __shared__ float ek[64][68];   // row-major [k][d]

    int tid = threadIdx.x;
    int blk = blockIdx.x;
    int kt = blk & 7;              // 8 k-tiles of 64
    int qt = (blk >> 3) & 3;       // 4 q-tiles of 128
    int bh = blk >> 5;

    const float4* __restrict__ eqg = (const float4*)(eq_all + (bh * L + qt * 128) * D);
    const float4* __restrict__ ekg = (const float4*)(ek_all + (bh * L + kt * 64) * D);

    #pragma unroll
    for (int i = 0; i < 6; ++i) {          // 192 rows x 16 float4 total
        int idx = tid + i * 512;
        int r = idx >> 4, c4 = idx & 15;
        if (r < 128) *(float4*)&eq[r][c4 * 4] = eqg[idx];
        else         *(float4*)&ek[r - 128][c4 * 4] = ekg[idx - 2048];
    }
    __syncthreads();

    int kg = tid & 15;
    int qg = tid >> 4;

    float acc[4][4] = {{0.f,0.f,0.f,0.f},{0.f,0.f,0.f,0.f},
                       {0.f,0.f,0.f,0.f},{0.f,0.f,0.f,0.f}};

    #pragma unroll 2
    for (int d8 = 0; d8 < 8; ++d8) {
        // eq: 4-address x 16-lane broadcast (free); ek: 16 rows, 2-way (free)
        float4 vq0a = *(const float4*)&eq[qg     ][d8 * 8];
        float4 vq0b = *(const float4*)&eq[qg     ][d8 * 8 + 4];
        float4 vq1a = *(const float4*)&eq[qg + 32][d8 * 8];
        float4 vq1b = *(const float4*)&eq[qg + 32][d8 * 8 + 4];
        float4 vq2a = *(const float4*)&eq[qg + 64][d8 * 8];
        float4 vq2b = *(const float4*)&eq[qg + 64][d8 * 8 + 4];
        float4 vq3a = *(const float4*)&eq[qg + 96][d8 * 8];
        float4 vq3b = *(const float4*)&eq[qg + 96][d8 * 8 + 4];
        float4 vk0a = *(const float4*)&ek[kg     ][d8 * 8];
        float4 vk0b = *(const float4*)&ek[kg     ][d8 * 8 + 4];
        float4 vk1a = *(const float4*)&ek[kg + 16][d8 * 8];
        float4 vk1b = *(const float4*)&ek[kg + 16][d8 * 8 + 4];
        float4 vk2a = *(const float4*)&ek[kg + 32][d8 * 8];
        float4 vk2b = *(const float4*)&ek[kg + 32][d8 * 8 + 4];
        float4 vk3a = *(const float4*)&ek[kg + 48][d8 * 8];
        float4 vk3b = *(const float4*)&ek[kg + 48][d8 * 8 + 4];
        // wave-uniform address -> scalar loads (SGPR operands)
        float4 vva  = *(const float4*)(Vv + d8 * 8);
        float4 vvb  = *(const float4*)(Vv + d8 * 8 + 4);

        OCT(acc[0][0], vq0a, vq0b, vk0a, vk0b, vva, vvb);
        OCT(acc[0][1], vq0a, vq0b, vk1a, vk1b, vva, vvb);
        OCT(acc[0][2], vq0a, vq0b, vk2a, vk2b, vva, vvb);
        OCT(acc[0][3], vq0a, vq0b, vk3a, vk3b, vva, vvb);
        OCT(acc[1][0], vq1a, vq1b, vk0a, vk0b, vva, vvb);
        OCT(acc[1][1], vq1a, vq1b, vk1a, vk1b, vva, vvb);
        OCT(acc[1][2], vq1a, vq1b, vk2a, vk2b, vva, vvb);
        OCT(acc[1][3], vq1a, vq1b, vk3a, vk3b, vva, vvb);
        OCT(acc[2][0], vq2a, vq2b, vk0a, vk0b, vva, vvb);
        OCT(acc[2][1], vq2a, vq2b, vk1a, vk1b, vva, vvb);
        OCT(acc[2][2], vq2a, vq2b, vk2a, vk2b, vva, vvb);
        OCT(acc[2][3], vq2a, vq2b, vk3a, vk3b, vva, vvb);
        OCT(acc[3][0], vq3a, vq3b, vk0a, vk0b, vva, vvb);
        OCT(acc[3][1], vq3a, vq3b, vk1a, vk1b, vva, vvb);
        OCT(acc[3][2], vq3a, vq3b, vk2a, vk2b, vva, vvb);
        OCT(acc[3][3], vq3a, vq3b, vk3a, vk3b, vva, vvb);
    }

    // sum(V): uniform scalar math, epilogue only
    float sv = 0.f;
    #pragma unroll
    for (int t = 0; t < 64; ++t) sv += Vv[t];

    // score = bV + sum(V) - 2 * sum_d V[d]/(1+e^{2x_d})
    float base = bV[0] + sv;
    int orow = (bh * L + qt * 128 + qg) * L + kt * 64 + kg;
    #pragma unroll
    for (int i = 0; i < 4; ++i) {
        #pragma unroll
        for (int j = 0; j < 4; ++j) {
            out[orow + (32 * i) * L + 16 * j] = fmaf(-2.f, acc[i][j], base);
        }
    }
}

extern "C" void kernel_launch(void* const* d_in, const int* in_sizes, int n_in,
                              void* d_out, int out_size, void* d_ws, size_t ws_size,
                              hipStream_t stream) {
    const float* Q  = (const float*)d_in[0];
    const float* K  = (const float*)d_in[1];
    const float* W1 = (const float*)d_in[2];
    const float* b1 = (const float*)d_in[3];
    const float* W2 = (const float*)d_in[4];
    const float* b2 = (const float*)d_in[5];
    const float* V  = (const float*)d_in[6];
    const float* bV = (const float*)d_in[7];
    float* out = (float*)d_out;

    float* eq_all = (float*)d_ws;                 // BH*L*D floats (2 MB)
    float* ek_all = eq_all + BH * L * D;          // BH*L*D floats (2 MB)

    proj_kernel<<<1024, 256, 0, stream>>>(Q, K, W1, b1, W2, b2, eq_all, ek_all);
    score_kernel<<<512, 512, 0, stream>>>(eq_all, ek_all, V, bV, out);
}